// Round 8
// baseline (275.239 us; speedup 1.0000x reference)
//
#include <hip/hip_runtime.h>

// ---------------------------------------------------------------------------
// PROFILING PROBE ROUND (deliberately slow, still bit-correct):
//  k_score body x5 and k_output body x8 inside their kernels, so each
//  dispatch exceeds the ~115 us harness poison-fills and surfaces in the
//  top-5 counter table with its own hbm_gbps / VALUBusy / Occupancy.
//  All math identical to round-6 (67.6 us best); writes are idempotent.
// ---------------------------------------------------------------------------

#define NSLICE 48
#define IMG    1048576
#define TILE   8

// --- K1 probe: round-6 k_score, body repeated 5x. --------------------------
__global__ __launch_bounds__(256) void k_score5(const float* x,
                                                double* part) {
  const int ph = blockIdx.x;   // patch row 0..31
  const int s  = blockIdx.y;   // slice 0..47
  const int t  = threadIdx.x;
  const float* base = x + (size_t)s * IMG + (size_t)ph * 32768 + 4 * t;
  const bool has_d3 = (t & 7) != 7;

  for (int it = 0; it < 5; ++it) {
    double s1x = 0.0, s2x = 0.0, s1y = 0.0, s2y = 0.0;

#define LD(r) (*(const float4*)(base + (size_t)(r) * 1024))
#define DX(v) { float nx = __shfl_down((v).x, 1);                              \
    float d0 = fabsf((v).y-(v).x), d1 = fabsf((v).z-(v).y),                    \
          d2 = fabsf((v).w-(v).z);                                             \
    float d3 = has_d3 ? fabsf(nx-(v).w) : 0.f;                                 \
    s1x += (double)((d0+d1)+(d2+d3));                                          \
    s2x += (double)((d0*d0+d1*d1)+(d2*d2+d3*d3)); }
#define DY(a,b) { float e0 = fabsf((b).x-(a).x), e1 = fabsf((b).y-(a).y),      \
                        e2 = fabsf((b).z-(a).z), e3 = fabsf((b).w-(a).w);      \
    s1y += (double)((e0+e1)+(e2+e3));                                          \
    s2y += (double)((e0*e0+e1*e1)+(e2*e2+e3*e3)); }

    float4 v0 = LD(0);
    for (int r = 0; r < 32; r += 8) {
      float4 w1 = LD(r + 1), w2 = LD(r + 2), w3 = LD(r + 3), w4 = LD(r + 4);
      float4 w5 = LD(r + 5), w6 = LD(r + 6), w7 = LD(r + 7);
      float4 w8;
      const bool more = (r + 8 < 32);
      if (more) w8 = LD(r + 8);
      DX(v0); DX(w1); DX(w2); DX(w3); DX(w4); DX(w5); DX(w6); DX(w7);
      DY(v0, w1); DY(w1, w2); DY(w2, w3); DY(w3, w4);
      DY(w4, w5); DY(w5, w6); DY(w6, w7);
      if (more) { DY(w7, w8); v0 = w8; }
    }
#undef LD
#undef DX
#undef DY

#pragma unroll
    for (int off = 4; off > 0; off >>= 1) {
      s1x += __shfl_down(s1x, off, 8);
      s2x += __shfl_down(s2x, off, 8);
      s1y += __shfl_down(s1y, off, 8);
      s2y += __shfl_down(s2y, off, 8);
    }
    if ((t & 7) == 0) {
      const int p = ph * 32 + (t >> 3);
      part[(size_t)(0 * NSLICE + s) * 1024 + p] = s1x;
      part[(size_t)(1 * NSLICE + s) * 1024 + p] = s2x;
      part[(size_t)(2 * NSLICE + s) * 1024 + p] = s1y;
      part[(size_t)(3 * NSLICE + s) * 1024 + p] = s2y;
    }
  }
}

// --- K2: round-6 verbatim. One block per patch, parallel loads + shfl tree.
__global__ __launch_bounds__(256) void k_finalize(const double* __restrict__ part,
                                                  double* __restrict__ scores) {
  const int p    = blockIdx.x;
  const int t    = threadIdx.x;
  const int q    = t >> 6;
  const int lane = t & 63;

  double v = 0.0;
  if (lane < NSLICE)
    v = part[(size_t)(q * NSLICE + lane) * 1024 + p];

#pragma unroll
  for (int off = 32; off > 0; off >>= 1) v += __shfl_down(v, off);

  __shared__ double S[4];
  if (lane == 0) S[q] = v;
  __syncthreads();

  if (t == 0) {
    const double N = 47616.0;
    double mx = S[0] / N, my = S[2] / N;
    double vx = (S[1] - S[0] * S[0] / N) / (N - 1.0);
    double vy = (S[3] - S[2] * S[2] / N) / (N - 1.0);
    scores[p] = 0.25 * (mx + my) * (vx + vy);
  }
}

// --- K3: round-6 verbatim. ------------------------------------------------
__global__ __launch_bounds__(256) void k_rank(const double* __restrict__ scores,
                                              int* __restrict__ sel) {
  __shared__ double sc[1024];
  const int t = threadIdx.x;
  for (int i = t; i < 1024; i += 256) sc[i] = scores[i];
  __syncthreads();

  const int c = blockIdx.x * 32 + (t >> 3);
  const double mine = sc[c];
  int rank = 0;
  for (int j = (t & 7); j < 1024; j += 8) {
    double vj = sc[j];
    rank += (vj < mine) || (vj == mine && j < c);
  }
#pragma unroll
  for (int off = 4; off > 0; off >>= 1) rank += __shfl_down(rank, off, 8);
  if ((t & 7) == 0) {
    if (rank < 9)          sel[9 + rank]    = c;
    else if (rank >= 1015) sel[rank - 1015] = c;
  }
}

// --- K4 probe: round-5/6 k_output (TILE=8), body repeated 8x. --------------
__global__ __launch_bounds__(256) void k_output8(const float* x,
                                                 const int* sel,
                                                 float* out) {
  const int ty  = blockIdx.x;              // 0..27
  const int blk = blockIdx.y;              // 0..95
  const int set = blk / 48;
  const int bc  = blk % 48;
  const int y0  = ty * TILE;

  __shared__ int   i0t[224];
  __shared__ float frt[224];
  __shared__ float R[6][97];
  __shared__ float H[6][224];
  __shared__ float U[10][224];
  __shared__ int   selm[9];
  const int t = threadIdx.x;

  for (int it = 0; it < 8; ++it) {
    if (t < 9) selm[t] = sel[set * 9 + t];
    if (t < 224) {
      int num = 3 * t - 2;
      int i0, fr7;
      if (num < 0) { i0 = 0; fr7 = 0; }
      else {
        i0 = num / 7; fr7 = num - i0 * 7;
        if (i0 >= 95) { i0 = 95; fr7 = 0; }
      }
      i0t[t] = i0;
      frt[t] = (float)fr7 * (1.0f / 7.0f);
    }
    __syncthreads();

    const int Ylo   = max(y0 - 1, 0);
    const int Yhi   = min(y0 + TILE, 223);
    const int sy_lo = i0t[Ylo];
    const int sy_hi = min(i0t[Yhi] + 1, 95);
    const int nrows = sy_hi - sy_lo + 1;     // <= 6

    const float* src = x + (size_t)bc * IMG;
    for (int idx = t; idx < nrows * 96; idx += 256) {
      int ry = idx / 96, xx = idx - ry * 96;
      int sy = sy_lo + ry;
      int gr = sy >> 5, i = sy & 31;
      int gc = xx >> 5, j = xx & 31;
      int pidx = selm[gr * 3 + gc];
      R[ry][xx] = src[(size_t)((pidx >> 5) * 32 + i) * 1024 + (pidx & 31) * 32 + j];
    }
    __syncthreads();

    for (int idx = t; idx < nrows * 224; idx += 256) {
      int r = idx / 224, X = idx - r * 224;
      int ix0 = i0t[X], ix1 = min(ix0 + 1, 95);
      float fx = frt[X];
      float a = R[r][ix0], b = R[r][ix1];
      H[r][X] = a + fx * (b - a);
    }
    __syncthreads();

    for (int idx = t; idx < 10 * 224; idx += 256) {
      int yy = idx / 224, X = idx - yy * 224;
      int Y = y0 - 1 + yy;
      if ((unsigned)Y < 224u) {
        int a = i0t[Y] - sy_lo;
        int b = min(i0t[Y] + 1, 95) - sy_lo;
        float fy = frt[Y];
        float h0 = H[a][X], h1 = H[b][X];
        U[yy][X] = h0 + fy * (h1 - h0);
      }
    }
    __syncthreads();

    const float F[3][3] = {{-1.f, 3.f, -1.f}, {3.f, -8.f, 3.f}, {-1.f, 3.f, -1.f}};
    float* o = out + (size_t)blk * (224 * 224);
    for (int idx = t; idx < TILE * 224; idx += 256) {
      int yy = idx / 224;
      int xx = idx - yy * 224;
      int y  = y0 + yy;
      float acc = 0.f;
#pragma unroll
      for (int dy = 0; dy < 3; ++dy) {
        int Y = y + dy - 1;
        if ((unsigned)Y >= 224u) continue;
        const float* Ur = U[yy + dy];
#pragma unroll
        for (int dx = 0; dx < 3; ++dx) {
          int X = xx + dx - 1;
          if ((unsigned)X >= 224u) continue;
          acc += F[dy][dx] * Ur[X];
        }
      }
      o[(size_t)y * 224 + xx] = acc;
    }
    __syncthreads();
  }
}

extern "C" void kernel_launch(void* const* d_in, const int* in_sizes, int n_in,
                              void* d_out, int out_size, void* d_ws, size_t ws_size,
                              hipStream_t stream) {
  const float* x = (const float*)d_in[0];
  float* out = (float*)d_out;

  double* part   = (double*)d_ws;                          // 4*48*1024*8 = 1.5 MB
  double* scores = (double*)((char*)d_ws + 1572864);       // 8 KB
  int*    sel    = (int*)((char*)d_ws + 1581056);          // 72 B

  k_score5  <<<dim3(32, 48), 256, 0, stream>>>(x, part);
  k_finalize<<<1024, 256, 0, stream>>>(part, scores);
  k_rank    <<<32, 256, 0, stream>>>(scores, sel);
  k_output8 <<<dim3(28, 96), 256, 0, stream>>>(x, sel, out);
}

// Round 9
// 67.988 us; speedup vs baseline: 4.0484x; 4.0484x over previous
//
#include <hip/hip_runtime.h>

// ---------------------------------------------------------------------------
// TextureAnalysisModule: x (16,3,1024,1024) f32
//  k_score    : per-(patch,slice) |dx|,|dy| partial sums (round-6 verbatim)
//  k_finalize : one block per patch; 192 parallel loads + shfl tree (r6)
//  k_rank     : stable rank-by-counting, scatter top9/bot9 indices (r6)
//  k_output   : TILE=16 strips; R -> H (x-bilerp) -> U (y-bilerp, zero-padded
//               edge rows) -> 3x3 SRM via 3-read/px register sweep
//  out: (2,16,3,224,224) f32
// ---------------------------------------------------------------------------

#define NSLICE 48
#define IMG    1048576
#define TILE   16

// --- K1: one block per (patch-row, slice); contiguous 32x1024 strip. -------
__global__ __launch_bounds__(256) void k_score(const float* __restrict__ x,
                                               double* __restrict__ part) {
  const int ph = blockIdx.x;   // patch row 0..31
  const int s  = blockIdx.y;   // slice 0..47
  const int t  = threadIdx.x;
  const float* base = x + (size_t)s * IMG + (size_t)ph * 32768 + 4 * t;

  double s1x = 0.0, s2x = 0.0, s1y = 0.0, s2y = 0.0;
  const bool has_d3 = (t & 7) != 7;   // col 4t+3 is not a patch boundary

#define LD(r) (*(const float4*)(base + (size_t)(r) * 1024))
#define DX(v) { float nx = __shfl_down((v).x, 1);                              \
    float d0 = fabsf((v).y-(v).x), d1 = fabsf((v).z-(v).y),                    \
          d2 = fabsf((v).w-(v).z);                                             \
    float d3 = has_d3 ? fabsf(nx-(v).w) : 0.f;                                 \
    s1x += (double)((d0+d1)+(d2+d3));                                          \
    s2x += (double)((d0*d0+d1*d1)+(d2*d2+d3*d3)); }
#define DY(a,b) { float e0 = fabsf((b).x-(a).x), e1 = fabsf((b).y-(a).y),      \
                        e2 = fabsf((b).z-(a).z), e3 = fabsf((b).w-(a).w);      \
    s1y += (double)((e0+e1)+(e2+e3));                                          \
    s2y += (double)((e0*e0+e1*e1)+(e2*e2+e3*e3)); }

  float4 v0 = LD(0);
  for (int r = 0; r < 32; r += 8) {
    float4 w1 = LD(r + 1), w2 = LD(r + 2), w3 = LD(r + 3), w4 = LD(r + 4);
    float4 w5 = LD(r + 5), w6 = LD(r + 6), w7 = LD(r + 7);
    float4 w8;
    const bool more = (r + 8 < 32);
    if (more) w8 = LD(r + 8);
    DX(v0); DX(w1); DX(w2); DX(w3); DX(w4); DX(w5); DX(w6); DX(w7);
    DY(v0, w1); DY(w1, w2); DY(w2, w3); DY(w3, w4);
    DY(w4, w5); DY(w5, w6); DY(w6, w7);
    if (more) { DY(w7, w8); v0 = w8; }
  }
#undef LD
#undef DX
#undef DY

#pragma unroll
  for (int off = 4; off > 0; off >>= 1) {
    s1x += __shfl_down(s1x, off, 8);
    s2x += __shfl_down(s2x, off, 8);
    s1y += __shfl_down(s1y, off, 8);
    s2y += __shfl_down(s2y, off, 8);
  }
  if ((t & 7) == 0) {
    const int p = ph * 32 + (t >> 3);
    part[(size_t)(0 * NSLICE + s) * 1024 + p] = s1x;
    part[(size_t)(1 * NSLICE + s) * 1024 + p] = s2x;
    part[(size_t)(2 * NSLICE + s) * 1024 + p] = s1y;
    part[(size_t)(3 * NSLICE + s) * 1024 + p] = s2y;
  }
}

// --- K2: one block per patch; wave q reduces quantity q over 48 slices. ----
__global__ __launch_bounds__(256) void k_finalize(const double* __restrict__ part,
                                                  double* __restrict__ scores) {
  const int p    = blockIdx.x;
  const int t    = threadIdx.x;
  const int q    = t >> 6;
  const int lane = t & 63;

  double v = 0.0;
  if (lane < NSLICE)
    v = part[(size_t)(q * NSLICE + lane) * 1024 + p];

#pragma unroll
  for (int off = 32; off > 0; off >>= 1) v += __shfl_down(v, off);

  __shared__ double S[4];
  if (lane == 0) S[q] = v;
  __syncthreads();

  if (t == 0) {
    const double N = 47616.0;  // 16*3*32*31
    double mx = S[0] / N, my = S[2] / N;
    double vx = (S[1] - S[0] * S[0] / N) / (N - 1.0);
    double vy = (S[3] - S[2] * S[2] / N) / (N - 1.0);
    scores[p] = 0.25 * (mx + my) * (vx + vy);
  }
}

// --- K3: stable rank; 8 lanes per candidate, 32 candidates per block. ------
__global__ __launch_bounds__(256) void k_rank(const double* __restrict__ scores,
                                              int* __restrict__ sel) {
  __shared__ double sc[1024];
  const int t = threadIdx.x;
  for (int i = t; i < 1024; i += 256) sc[i] = scores[i];
  __syncthreads();

  const int c = blockIdx.x * 32 + (t >> 3);
  const double mine = sc[c];
  int rank = 0;
  for (int j = (t & 7); j < 1024; j += 8) {
    double vj = sc[j];
    rank += (vj < mine) || (vj == mine && j < c);
  }
#pragma unroll
  for (int off = 4; off > 0; off >>= 1) rank += __shfl_down(rank, off, 8);
  if ((t & 7) == 0) {
    if (rank < 9)          sel[9 + rank]    = c;
    else if (rank >= 1015) sel[rank - 1015] = c;
  }
}

// --- K4: one block per (image, 16-row output strip). -----------------------
// R (<=10x96) -> H (x-bilerp, <=10 rows) -> U (y-bilerp, 18 rows incl zero
// pad rows) -> 3x3 SRM via A/M register sweep (3 LDS reads per pixel).
__global__ __launch_bounds__(256) void k_output(const float* __restrict__ x,
                                                const int* __restrict__ sel,
                                                float* __restrict__ out) {
  const int ty  = blockIdx.x;              // 0..13
  const int blk = blockIdx.y;              // 0..95 = set*48 + (b*3+c)
  const int set = blk / 48;
  const int bc  = blk % 48;
  const int y0  = ty * TILE;

  __shared__ int   i0t[224];
  __shared__ float frt[224];
  __shared__ float R[10][97];
  __shared__ float H[10][225];
  __shared__ float U[18][225];
  __shared__ int   selm[9];
  const int t = threadIdx.x;

  if (t < 9) selm[t] = sel[set * 9 + t];
  if (t < 224) {
    // src coord = (t+0.5)*96/224 - 0.5 = (3t-2)/7 ; edge renorm == clamp
    int num = 3 * t - 2;
    int i0, fr7;
    if (num < 0) { i0 = 0; fr7 = 0; }
    else {
      i0 = num / 7; fr7 = num - i0 * 7;
      if (i0 >= 95) { i0 = 95; fr7 = 0; }
    }
    i0t[t] = i0;
    frt[t] = (float)fr7 * (1.0f / 7.0f);
  }
  __syncthreads();

  const int Ylo   = max(y0 - 1, 0);
  const int Yhi   = min(y0 + TILE, 223);
  const int sy_lo = i0t[Ylo];
  const int sy_hi = min(i0t[Yhi] + 1, 95);
  const int nrows = sy_hi - sy_lo + 1;     // <= 10

  // gather source rows
  const float* src = x + (size_t)bc * IMG;
  for (int idx = t; idx < nrows * 96; idx += 256) {
    int ry = idx / 96, xx = idx - ry * 96;
    int sy = sy_lo + ry;
    int gr = sy >> 5, i = sy & 31;
    int gc = xx >> 5, j = xx & 31;
    int pidx = selm[gr * 3 + gc];
    R[ry][xx] = src[(size_t)((pidx >> 5) * 32 + i) * 1024 + (pidx & 31) * 32 + j];
  }
  __syncthreads();

  // horizontal bilerp
  for (int idx = t; idx < nrows * 224; idx += 256) {
    int r = idx / 224, X = idx - r * 224;
    int ix0 = i0t[X], ix1 = min(ix0 + 1, 95);
    float fx = frt[X];
    float a = R[r][ix0], b = R[r][ix1];
    H[r][X] = a + fx * (b - a);
  }
  __syncthreads();

  // vertical bilerp rows Y = y0-1 .. y0+TILE (18 rows); out-of-range -> 0
  for (int idx = t; idx < (TILE + 2) * 224; idx += 256) {
    int yy = idx / 224, X = idx - yy * 224;
    int Y = y0 - 1 + yy;
    if ((unsigned)Y < 224u) {
      int a = i0t[Y] - sy_lo;
      int b = min(i0t[Y] + 1, 95) - sy_lo;
      float fy = frt[Y];
      float h0 = H[a][X], h1 = H[b][X];
      U[yy][X] = h0 + fy * (h1 - h0);
    } else {
      U[yy][X] = 0.f;   // conv zero padding via zero rows
    }
  }
  __syncthreads();

  // 3x3 SRM: acc = 3(A(x)+M(x-1)+M(x+1)) - A(x-1) - A(x+1) - 8 M(x)
  // A(x)=U[yy][x]+U[yy+2][x], M(x)=U[yy+1][x].  14-px run per thread.
  {
    const int yy = t >> 4;           // 0..15
    const int xs = (t & 15) * 14;    // 0,14,...,210
    const int y  = y0 + yy;
    float* o = out + (size_t)blk * (224 * 224) + (size_t)y * 224;

    float aP, mP, aC, mC;
    if (xs > 0) {
      aP = U[yy][xs - 1] + U[yy + 2][xs - 1];
      mP = U[yy + 1][xs - 1];
    } else { aP = 0.f; mP = 0.f; }
    aC = U[yy][xs] + U[yy + 2][xs];
    mC = U[yy + 1][xs];

#pragma unroll
    for (int i = 0; i < 14; ++i) {
      const int xx = xs + i;
      float aN, mN;
      if (xx < 223) {
        aN = U[yy][xx + 1] + U[yy + 2][xx + 1];
        mN = U[yy + 1][xx + 1];
      } else { aN = 0.f; mN = 0.f; }
      o[xx] = 3.f * (aC + mP + mN) - (aP + aN) - 8.f * mC;
      aP = aC; aC = aN; mP = mC; mC = mN;
    }
  }
}

extern "C" void kernel_launch(void* const* d_in, const int* in_sizes, int n_in,
                              void* d_out, int out_size, void* d_ws, size_t ws_size,
                              hipStream_t stream) {
  const float* x = (const float*)d_in[0];
  float* out = (float*)d_out;

  double* part   = (double*)d_ws;                          // 4*48*1024*8 = 1.5 MB
  double* scores = (double*)((char*)d_ws + 1572864);       // 8 KB
  int*    sel    = (int*)((char*)d_ws + 1581056);          // 72 B

  k_score   <<<dim3(32, 48), 256, 0, stream>>>(x, part);
  k_finalize<<<1024, 256, 0, stream>>>(part, scores);
  k_rank    <<<32, 256, 0, stream>>>(scores, sel);
  k_output  <<<dim3(14, 96), 256, 0, stream>>>(x, sel, out);
}